// Round 9
// baseline (250.558 us; speedup 1.0000x reference)
//
#include <hip/hip_runtime.h>

typedef unsigned char u8;
typedef float f32x4 __attribute__((ext_vector_type(4)));
typedef _Float16 f16x8 __attribute__((ext_vector_type(8)));

#define DIM 128

__device__ __forceinline__ float fast_tanh(float x) {
    // tanh(x) = 1 - 2/(exp2(2x*log2e)+1); exact +-1 saturation via inf->0
    float e = __builtin_amdgcn_exp2f(x * 2.885390081777927f);
    return 1.0f - 2.0f * __builtin_amdgcn_rcpf(e + 1.0f);
}
__device__ __forceinline__ float fast_sigmoid(float x) {
    float e = __builtin_amdgcn_exp2f(x * -1.4426950408889634f);
    return __builtin_amdgcn_rcpf(1.0f + e);
}

// stage W2^T (fp16, XOR-swizzled 16B chunks) into LDS; call with 512 threads
__device__ __forceinline__ void stage_w2(const float* __restrict__ W2,
                                         _Float16* sW2T, int tid) {
    #pragma unroll
    for (int s = 0; s < 4; ++s) {
        int chunk = s * 512 + tid;       // 0..2047
        int n = chunk & 127, ko = chunk >> 7;
        f16x8 v;
        #pragma unroll
        for (int qq = 0; qq < 8; ++qq)
            v[qq] = (_Float16)W2[(ko * 8 + qq) * DIM + n];   // coalesced over n
        int slot = ko ^ (n & 15);
        *(f16x8*)&sW2T[n * DIM + slot * 8] = v;
    }
}

// one wave evaluates 32 points (2 A-frags x 16 rows) x 128 out-dims.
// rs[mf][rg] = sum_c tanh(h2+b2)*W3 (lane-reduced, valid on all lanes).
// C/D layout: point-row = mf*16 + lg*4 + rg.
__device__ __forceinline__ void mlp_wave(
    const float xs[2], const float ys[2], const _Float16* sW2T,
    const float* __restrict__ W1, const float* __restrict__ b1,
    const float* __restrict__ b2, const float* __restrict__ W3,
    int lg, int l15, float rs[2][4])
{
    f32x4 acc[2][8];
    #pragma unroll
    for (int mf = 0; mf < 2; ++mf)
        #pragma unroll
        for (int nf = 0; nf < 8; ++nf) acc[mf][nf] = (f32x4)(0.0f);

    #pragma unroll
    for (int kf = 0; kf < 4; ++kf) {
        const int kbase = kf * 32 + lg * 8;
        f16x8 bh[8];
        #pragma unroll
        for (int nf = 0; nf < 8; ++nf) {
            int cc = nf * 16 + l15;
            int slot = (kf * 4 + lg) ^ l15;   // matches stage_w2 swizzle
            bh[nf] = *(const f16x8*)&sW2T[cc * DIM + slot * 8];
        }
        f32x4 wxa = *(const f32x4*)&W1[kbase];
        f32x4 wxb = *(const f32x4*)&W1[kbase + 4];
        f32x4 wya = *(const f32x4*)&W1[DIM + kbase];
        f32x4 wyb = *(const f32x4*)&W1[DIM + kbase + 4];
        f32x4 b1a = *(const f32x4*)&b1[kbase];
        f32x4 b1b = *(const f32x4*)&b1[kbase + 4];
        f16x8 ah[2];
        #pragma unroll
        for (int mf = 0; mf < 2; ++mf) {
            float x = xs[mf], y = ys[mf];
            #pragma unroll
            for (int qq = 0; qq < 4; ++qq)
                ah[mf][qq] = (_Float16)fast_tanh(fmaf(x, wxa[qq], fmaf(y, wya[qq], b1a[qq])));
            #pragma unroll
            for (int qq = 0; qq < 4; ++qq)
                ah[mf][4 + qq] = (_Float16)fast_tanh(fmaf(x, wxb[qq], fmaf(y, wyb[qq], b1b[qq])));
        }
        #pragma unroll
        for (int nf = 0; nf < 8; ++nf)
            #pragma unroll
            for (int mf = 0; mf < 2; ++mf)
                acc[mf][nf] = __builtin_amdgcn_mfma_f32_16x16x32_f16(ah[mf], bh[nf], acc[mf][nf], 0, 0, 0);
    }

    #pragma unroll
    for (int mf = 0; mf < 2; ++mf)
        #pragma unroll
        for (int rg = 0; rg < 4; ++rg) rs[mf][rg] = 0.0f;
    #pragma unroll
    for (int nf = 0; nf < 8; ++nf) {
        int cc = nf * 16 + l15;
        float w3v = W3[cc], b2v = b2[cc];
        #pragma unroll
        for (int mf = 0; mf < 2; ++mf)
            #pragma unroll
            for (int rg = 0; rg < 4; ++rg)
                rs[mf][rg] += fast_tanh(acc[mf][nf][rg] + b2v) * w3v;
    }
    #pragma unroll
    for (int mf = 0; mf < 2; ++mf)
        #pragma unroll
        for (int rg = 0; rg < 4; ++rg) {
            float v = rs[mf][rg];
            v += __shfl_xor(v, 1);
            v += __shfl_xor(v, 2);
            v += __shfl_xor(v, 4);
            v += __shfl_xor(v, 8);
            rs[mf][rg] = v;
        }
}

// ---- dense eval of the 33x33 base grid (5 blocks x 256 points) ----
__global__ __launch_bounds__(512, 4) void eval_base(
    const float* __restrict__ W1, const float* __restrict__ b1,
    const float* __restrict__ W2, const float* __restrict__ b2,
    const float* __restrict__ W3, const float* __restrict__ b3,
    const float* __restrict__ bmin, const float* __restrict__ bmax,
    float* __restrict__ occ0)
{
    __shared__ __align__(16) _Float16 sW2T[DIM * DIM];
    const int R = 33, N = 1089;
    const int tid = threadIdx.x;
    stage_w2(W2, sW2T, tid);

    const int w = tid >> 6, lane = tid & 63;
    const int l15 = lane & 15, lg = lane >> 4;
    const int m0 = blockIdx.x * 256;
    const float inv = 1.0f / 32.0f;
    const float bx0 = bmin[0], by0 = bmin[1];
    const float sx = bmax[0] - bx0, sy = bmax[1] - by0;
    float xs[2], ys[2];
    #pragma unroll
    for (int mf = 0; mf < 2; ++mf) {
        int pi = m0 + w * 32 + mf * 16 + l15;
        int pg = (pi < N) ? pi : N - 1;
        int gi = pg / R, gj = pg - gi * R;
        xs[mf] = bx0 + (float)gj * inv * sx;
        ys[mf] = by0 + (float)gi * inv * sy;
    }
    __syncthreads();

    float rs[2][4];
    mlp_wave(xs, ys, sW2T, W1, b1, b2, W3, lg, l15, rs);
    if (l15 == 0) {
        float b3v = b3[0];
        #pragma unroll
        for (int mf = 0; mf < 2; ++mf)
            #pragma unroll
            for (int rg = 0; rg < 4; ++rg) {
                int po = m0 + w * 32 + mf * 16 + lg * 4 + rg;
                if (po < N) occ0[po] = fast_sigmoid(rs[mf][rg] + b3v);
            }
    }
}

// ---- A: per 32x32 fine tile, compute raw + dilate^4 need-mask, append
//      needed (& not inherited-calc) core cells to the global worklist ----
#define NT 512
__global__ __launch_bounds__(NT) void build_wl(
    const float* __restrict__ occP, int Rp, const u8* __restrict__ calcP,
    int R, int* __restrict__ wl, int* __restrict__ cnt)
{
    __shared__ u8 sRaw[40 * 40], sTmp[40 * 40];
    __shared__ int sList[32 * 32];
    __shared__ int lCnt, sBase;
    const int nT = (R + 31) / 32;
    const int bi = blockIdx.x / nT, bj = blockIdx.x - bi * nT;
    const int fi0 = bi * 32 - 4, fj0 = bj * 32 - 4;
    const int tid = threadIdx.x;
    if (tid == 0) lCnt = 0;

    bool anyRaw = false;
    for (int c = tid; c < 1600; c += NT) {
        int li = c / 40, lj = c - li * 40;
        int fi = fi0 + li, fj = fj0 + lj;
        u8 rw = 0;
        if (fi >= 0 && fi < R && fj >= 0 && fj < R) {
            int ip = fi >> 1, jp = fj >> 1, oi = fi & 1, oj = fj & 1;
            if (oi | oj) {
                bool m0 = occP[ip * Rp + jp] > 0.5f;
                bool b;
                if (oi && !oj)      b = m0 != (occP[(ip + 1) * Rp + jp] > 0.5f);
                else if (!oi && oj) b = m0 != (occP[ip * Rp + jp + 1] > 0.5f);
                else {
                    bool m1 = occP[(ip + 1) * Rp + jp] > 0.5f;
                    bool m2 = occP[ip * Rp + jp + 1] > 0.5f;
                    bool m3 = occP[(ip + 1) * Rp + jp + 1] > 0.5f;
                    b = (m0 | m1 | m2 | m3) && !(m0 & m1 & m2 & m3);
                }
                rw = b ? 1 : 0;
            }
        }
        sRaw[c] = rw;
        anyRaw |= (rw != 0);
    }
    if (!__syncthreads_or(anyRaw ? 1 : 0)) return;

    // separable dilate +-4: rows -> sTmp
    for (int c = tid; c < 1600; c += NT) {
        int li = c / 40, lj = c - li * 40;
        int j0 = lj - 4 < 0 ? 0 : lj - 4, j1 = lj + 4 > 39 ? 39 : lj + 4;
        u8 a = 0;
        for (int jj = j0; jj <= j1; ++jj) a |= sRaw[li * 40 + jj];
        sTmp[c] = a;
    }
    __syncthreads();
    // cols + append core cells
    for (int c = tid; c < 1600; c += NT) {
        int li = c / 40, lj = c - li * 40;
        if (li < 4 || li >= 36 || lj < 4 || lj >= 36) continue;
        int fi = fi0 + li, fj = fj0 + lj;
        if (fi >= R || fj >= R) continue;       // fi,fj >= 0 guaranteed
        u8 a = 0;
        for (int ii = li - 4; ii <= li + 4; ++ii) a |= sTmp[ii * 40 + lj];
        if (!a) continue;
        bool cal = (((fi | fj) & 1) == 0)
                       ? (calcP ? (calcP[(fi >> 1) * Rp + (fj >> 1)] != 0) : true)
                       : false;
        if (cal) continue;
        int p = atomicAdd(&lCnt, 1);
        sList[p] = fi * R + fj;
    }
    __syncthreads();
    if (tid == 0) sBase = lCnt ? atomicAdd(cnt, lCnt) : 0;
    __syncthreads();
    for (int i = tid; i < lCnt; i += NT) wl[sBase + i] = sList[i];
}

// ---- B: MFMA MLP eval over the worklist (fixed grid, grid-stride) ----
__global__ __launch_bounds__(512, 4) void eval_wl(
    const float* __restrict__ W1, const float* __restrict__ b1,
    const float* __restrict__ W2, const float* __restrict__ b2,
    const float* __restrict__ W3, const float* __restrict__ b3,
    const float* __restrict__ bmin, const float* __restrict__ bmax,
    const int* __restrict__ wl, const int* __restrict__ cnt_p, int R,
    float* __restrict__ qbuf)
{
    const int cnt = *cnt_p;
    if ((int)blockIdx.x * 256 >= cnt) return;
    __shared__ __align__(16) _Float16 sW2T[DIM * DIM];
    const int tid = threadIdx.x;
    stage_w2(W2, sW2T, tid);

    const int w = tid >> 6, lane = tid & 63;
    const int l15 = lane & 15, lg = lane >> 4;
    const float inv = 1.0f / (float)(R - 1);    // R-1 pow2 -> exact
    const float bx0 = bmin[0], by0 = bmin[1];
    const float sx = bmax[0] - bx0, sy = bmax[1] - by0;
    __syncthreads();

    for (int base = blockIdx.x * 256; base < cnt; base += gridDim.x * 256) {
        float xs[2], ys[2];
        #pragma unroll
        for (int mf = 0; mf < 2; ++mf) {
            int g = base + w * 32 + mf * 16 + l15;
            int cell = wl[g < cnt ? g : cnt - 1];
            int gi = cell / R, gj = cell - gi * R;
            xs[mf] = bx0 + (float)gj * inv * sx;
            ys[mf] = by0 + (float)gi * inv * sy;
        }
        float rs[2][4];
        mlp_wave(xs, ys, sW2T, W1, b1, b2, W3, lg, l15, rs);
        if (l15 == 0) {
            float b3v = b3[0];
            #pragma unroll
            for (int mf = 0; mf < 2; ++mf)
                #pragma unroll
                for (int rg = 0; rg < 4; ++rg) {
                    int g = base + w * 32 + mf * 16 + lg * 4 + rg;
                    if (g < cnt) qbuf[wl[g]] = fast_sigmoid(rs[mf][rg] + b3v);
                }
        }
    }
}

// ---- C: per level resolve: upsample + raw + boundary + 3 conflict iters ----
template<int TS>
__global__ __launch_bounds__(NT) void level_kernel(
    const float* __restrict__ occP, const u8* __restrict__ calcP, int Rp,
    const float* __restrict__ q,
    float* __restrict__ occOut, u8* __restrict__ calcOut, int R)
{
    constexpr int HW = TS + 8;
    __shared__ float sOcc[HW * HW], sQ[HW * HW];
    __shared__ u8 sRaw[HW * HW], sCalc[HW * HW], sCfA[HW * HW], sCfB[HW * HW];
    const int nT = (R + TS - 1) / TS;
    const int bi = blockIdx.x / nT, bj = blockIdx.x - bi * nT;
    const int fi0 = bi * TS - 4, fj0 = bj * TS - 4;
    const int tid = threadIdx.x;
    const float BAL = 0.5f;

    bool anyRaw = false;
    for (int c = tid; c < HW * HW; c += NT) {
        int li = c / HW, lj = c - li * HW;
        int fi = fi0 + li, fj = fj0 + lj;
        float occi = 0.5f, qv = 0.5f; u8 rw = 0, cal = 0;
        if (fi >= 0 && fi < R && fj >= 0 && fj < R) {
            int ip = fi >> 1, jp = fj >> 1;
            float tl = occP[ip * Rp + jp];
            int oi = fi & 1, oj = fj & 1;
            bool b;
            if (!oi && !oj) { occi = tl; b = false; }
            else if (oi && !oj) {
                float bl = occP[(ip + 1) * Rp + jp];
                occi = 0.5f * (tl + bl);
                b = (tl > BAL) != (bl > BAL);
            } else if (!oi && oj) {
                float tr = occP[ip * Rp + jp + 1];
                occi = 0.5f * (tl + tr);
                b = (tl > BAL) != (tr > BAL);
            } else {
                float bl = occP[(ip + 1) * Rp + jp];
                float tr = occP[ip * Rp + jp + 1];
                float br = occP[(ip + 1) * Rp + jp + 1];
                occi = 0.5f * (0.5f * (tl + bl) + 0.5f * (tr + br)); // exact _up2 order
                bool m0 = tl > BAL, m1 = bl > BAL, m2 = tr > BAL, m3 = br > BAL;
                b = (m0 | m1 | m2 | m3) && !(m0 & m1 & m2 & m3);
            }
            rw = b ? 1 : 0;
            if (((fi | fj) & 1) == 0) cal = calcP ? calcP[ip * Rp + jp] : 1;
            qv = q[fi * R + fj];
        }
        sOcc[c] = occi; sQ[c] = qv; sRaw[c] = rw; sCalc[c] = cal;
        sCfA[c] = 0; sCfB[c] = 0;
        anyRaw |= (rw != 0);
    }

    if (__syncthreads_or(anyRaw ? 1 : 0)) {
        bool anyCf = false;
        for (int c = tid; c < HW * HW; c += NT) {
            int li = c / HW, lj = c - li * HW;
            if (li < 1 || li >= HW - 1 || lj < 1 || lj >= HW - 1) continue;
            int fi = fi0 + li, fj = fj0 + lj;
            if (fi < 0 || fi >= R || fj < 0 || fj >= R) continue;
            bool b = false;
            #pragma unroll
            for (int di = -1; di <= 1; ++di)
                #pragma unroll
                for (int dj = -1; dj <= 1; ++dj)
                    if (sRaw[(li + di) * HW + (lj + dj)]) b = true;
            b = b && !sCalc[c];
            float oi = sOcc[c], qq = sQ[c];
            u8 cf = (b && (oi - BAL) * (qq - BAL) < 0.0f) ? 1 : 0;
            if (b) { sOcc[c] = qq; sCalc[c] = 1; }
            sCfA[c] = cf;
            anyCf |= (cf != 0);
        }
        int haveCf = __syncthreads_or(anyCf ? 1 : 0);

        for (int it = 0; it < 3 && haveCf; ++it) {
            const u8* cin = (it & 1) ? sCfB : sCfA;
            u8* cout      = (it & 1) ? sCfA : sCfB;
            int lo = 2 + it, hi = HW - 2 - it;
            bool anyNc = false;
            for (int c = tid; c < HW * HW; c += NT) {
                int li = c / HW, lj = c - li * HW;
                if (li < lo || li >= hi || lj < lo || lj >= hi) continue;
                int fi = fi0 + li, fj = fj0 + lj;
                if (fi < 0 || fi >= R || fj < 0 || fj >= R) continue;
                bool any = false;
                #pragma unroll
                for (int di = -1; di <= 1; ++di)
                    #pragma unroll
                    for (int dj = -1; dj <= 1; ++dj)
                        if (cin[(li + di) * HW + (lj + dj)]) any = true;
                bool cand = any && !sCalc[c];
                float oc = sOcc[c], qq = sQ[c];
                u8 nc = (cand && (oc - BAL) * (qq - BAL) < 0.0f) ? 1 : 0;
                if (cand) { sOcc[c] = qq; sCalc[c] = 1; }
                cout[c] = nc;
                anyNc |= (nc != 0);
            }
            haveCf = __syncthreads_or(anyNc ? 1 : 0);
        }
    }

    for (int c = tid; c < HW * HW; c += NT) {
        int li = c / HW, lj = c - li * HW;
        if (li < 4 || li >= HW - 4 || lj < 4 || lj >= HW - 4) continue;
        int fi = fi0 + li, fj = fj0 + lj;
        if (fi < 0 || fi >= R || fj < 0 || fj >= R) continue;
        occOut[fi * R + fj] = sOcc[c];
        calcOut[fi * R + fj] = sCalc[c];
    }
}

extern "C" void kernel_launch(void* const* d_in, const int* in_sizes, int n_in,
                              void* d_out, int out_size, void* d_ws, size_t ws_size,
                              hipStream_t stream) {
    const float* W1   = (const float*)d_in[0];
    const float* b1   = (const float*)d_in[1];
    const float* W2   = (const float*)d_in[2];
    const float* b2   = (const float*)d_in[3];
    const float* W3   = (const float*)d_in[4];
    const float* b3   = (const float*)d_in[5];
    const float* bmin = (const float*)d_in[6];
    const float* bmax = (const float*)d_in[7];

    const int N33 = 1089, N513 = 513 * 513;

    float* occ0 = (float*)d_ws;
    float* qbuf = occ0 + N33;
    float* occA = qbuf + N513;
    float* occB = occA + N513;
    int*   wl   = (int*)(occB + N513);
    int*   cnts = wl + N513;
    u8* calcA = (u8*)(cnts + 4);
    u8* calcB = calcA + N513;
    float* out = (float*)d_out;

    hipMemsetAsync(cnts, 0, 4 * sizeof(int), stream);
    eval_base<<<5, 512, 0, stream>>>(W1, b1, W2, b2, W3, b3, bmin, bmax, occ0);

    // level 1: R=65
    build_wl<<<9, NT, 0, stream>>>(occ0, 33, (const u8*)nullptr, 65, wl, cnts + 0);
    eval_wl<<<32, 512, 0, stream>>>(W1, b1, W2, b2, W3, b3, bmin, bmax,
                                    wl, cnts + 0, 65, qbuf);
    level_kernel<8><<<81, NT, 0, stream>>>(occ0, (const u8*)nullptr, 33,
                                           qbuf, occA, calcB, 65);
    // level 2: R=129
    build_wl<<<25, NT, 0, stream>>>(occA, 65, calcB, 129, wl, cnts + 1);
    eval_wl<<<64, 512, 0, stream>>>(W1, b1, W2, b2, W3, b3, bmin, bmax,
                                    wl, cnts + 1, 129, qbuf);
    level_kernel<16><<<81, NT, 0, stream>>>(occA, calcB, 65,
                                            qbuf, occB, calcA, 129);
    // level 3: R=257
    build_wl<<<81, NT, 0, stream>>>(occB, 129, calcA, 257, wl, cnts + 2);
    eval_wl<<<96, 512, 0, stream>>>(W1, b1, W2, b2, W3, b3, bmin, bmax,
                                    wl, cnts + 2, 257, qbuf);
    level_kernel<32><<<81, NT, 0, stream>>>(occB, calcA, 129,
                                            qbuf, occA, calcB, 257);
    // level 4: R=513
    build_wl<<<289, NT, 0, stream>>>(occA, 257, calcB, 513, wl, cnts + 3);
    eval_wl<<<128, 512, 0, stream>>>(W1, b1, W2, b2, W3, b3, bmin, bmax,
                                     wl, cnts + 3, 513, qbuf);
    level_kernel<32><<<289, NT, 0, stream>>>(occA, calcB, 257,
                                             qbuf, out, calcA, 513);
}

// Round 10
// 72.410 us; speedup vs baseline: 3.4603x; 3.4603x over previous
//
#include <hip/hip_runtime.h>

typedef unsigned char u8;
typedef float f32x4 __attribute__((ext_vector_type(4)));
typedef _Float16 f16x8 __attribute__((ext_vector_type(8)));

#define DIM 128
#define TM  512   // points per block (8 waves x 64 points)

__device__ __forceinline__ float fast_tanh(float x) {
    // tanh(x) = 1 - 2/(exp2(2x*log2e)+1); exact +-1 saturation via inf->0
    float e = __builtin_amdgcn_exp2f(x * 2.885390081777927f);
    return 1.0f - 2.0f * __builtin_amdgcn_rcpf(e + 1.0f);
}
__device__ __forceinline__ float fast_sigmoid(float x) {
    float e = __builtin_amdgcn_exp2f(x * -1.4426950408889634f);
    return __builtin_amdgcn_rcpf(1.0f + e);
}

// ---- dense MLP eval of the 513x513 grid only ----
// (coarser grids are exact subsets: u=(j*2^s)/512 == j/(R_l-1), bit-identical)
// 8 waves/block, each wave: 64 points (4 A-frags) x 128 out-dims, W2^T fp16 LDS.
// mf=4 gives 32 independent tanh chains per phase per lane (ILP >> dep latency).
__global__ __launch_bounds__(512, 2) void eval_q4(
    const float* __restrict__ W1, const float* __restrict__ b1,
    const float* __restrict__ W2, const float* __restrict__ b2,
    const float* __restrict__ W3, const float* __restrict__ b3,
    const float* __restrict__ bmin, const float* __restrict__ bmax,
    float* __restrict__ q4)
{
    __shared__ __align__(16) _Float16 sW2T[DIM * DIM];   // 32 KB

    const int R = 513;
    const int N = R * R;                 // 263169
    const int tid = threadIdx.x;
    const int m0 = blockIdx.x * TM;

    // ---- stage W2T into LDS (fp16, XOR-swizzled 16B chunks) ----
    #pragma unroll
    for (int s = 0; s < 4; ++s) {
        int chunk = s * 512 + tid;       // 0..2047
        int n = chunk & 127, ko = chunk >> 7;
        f16x8 v;
        #pragma unroll
        for (int qq = 0; qq < 8; ++qq)
            v[qq] = (_Float16)W2[(ko * 8 + qq) * DIM + n];   // coalesced over n
        int slot = ko ^ (n & 15);
        *(f16x8*)&sW2T[n * DIM + slot * 8] = v;
    }

    const int w = tid >> 6, lane = tid & 63;
    const int l15 = lane & 15, lg = lane >> 4;

    const float inv = 1.0f / 512.0f;     // exact
    const float bx0 = bmin[0], by0 = bmin[1];
    const float sx = bmax[0] - bx0, sy = bmax[1] - by0;
    float xs[4], ys[4];
    #pragma unroll
    for (int mf = 0; mf < 4; ++mf) {
        int pi = m0 + w * 64 + mf * 16 + l15;
        int pg = (pi < N) ? pi : N - 1;
        int gi = pg / R, gj = pg - gi * R;
        xs[mf] = bx0 + (float)gj * inv * sx;
        ys[mf] = by0 + (float)gi * inv * sy;
    }

    f32x4 acc[4][8];
    #pragma unroll
    for (int mf = 0; mf < 4; ++mf)
        #pragma unroll
        for (int nf = 0; nf < 8; ++nf) acc[mf][nf] = (f32x4)(0.0f);

    __syncthreads();

    #pragma unroll
    for (int kf = 0; kf < 4; ++kf) {
        const int kbase = kf * 32 + lg * 8;
        f16x8 bh[8];
        #pragma unroll
        for (int nf = 0; nf < 8; ++nf) {
            int c = nf * 16 + l15;
            int slot = (kf * 4 + lg) ^ l15;   // matches write swizzle (c&15==l15)
            bh[nf] = *(const f16x8*)&sW2T[c * DIM + slot * 8];
        }
        f32x4 wxa = *(const f32x4*)&W1[kbase];
        f32x4 wxb = *(const f32x4*)&W1[kbase + 4];
        f32x4 wya = *(const f32x4*)&W1[DIM + kbase];
        f32x4 wyb = *(const f32x4*)&W1[DIM + kbase + 4];
        f32x4 b1a = *(const f32x4*)&b1[kbase];
        f32x4 b1b = *(const f32x4*)&b1[kbase + 4];
        f16x8 ah[4];
        #pragma unroll
        for (int mf = 0; mf < 4; ++mf) {
            float x = xs[mf], y = ys[mf];
            #pragma unroll
            for (int qq = 0; qq < 4; ++qq)
                ah[mf][qq] = (_Float16)fast_tanh(fmaf(x, wxa[qq], fmaf(y, wya[qq], b1a[qq])));
            #pragma unroll
            for (int qq = 0; qq < 4; ++qq)
                ah[mf][4 + qq] = (_Float16)fast_tanh(fmaf(x, wxb[qq], fmaf(y, wyb[qq], b1b[qq])));
        }
        #pragma unroll
        for (int nf = 0; nf < 8; ++nf)
            #pragma unroll
            for (int mf = 0; mf < 4; ++mf)
                acc[mf][nf] = __builtin_amdgcn_mfma_f32_16x16x32_f16(ah[mf], bh[nf], acc[mf][nf], 0, 0, 0);
    }

    // epilogue in registers; C/D: row = w*64+mf*16+lg*4+rg, col = nf*16+l15
    float rs[4][4] = {{0,0,0,0},{0,0,0,0},{0,0,0,0},{0,0,0,0}};
    #pragma unroll
    for (int nf = 0; nf < 8; ++nf) {
        int c = nf * 16 + l15;
        float w3v = W3[c], b2v = b2[c];
        #pragma unroll
        for (int mf = 0; mf < 4; ++mf)
            #pragma unroll
            for (int rg = 0; rg < 4; ++rg)
                rs[mf][rg] += fast_tanh(acc[mf][nf][rg] + b2v) * w3v;
    }
    #pragma unroll
    for (int mf = 0; mf < 4; ++mf)
        #pragma unroll
        for (int rg = 0; rg < 4; ++rg) {
            float v = rs[mf][rg];
            v += __shfl_xor(v, 1);
            v += __shfl_xor(v, 2);
            v += __shfl_xor(v, 4);
            v += __shfl_xor(v, 8);
            rs[mf][rg] = v;
        }
    if (l15 == 0) {
        float b3v = b3[0];
        #pragma unroll
        for (int mf = 0; mf < 4; ++mf)
            #pragma unroll
            for (int rg = 0; rg < 4; ++rg) {
                int po = m0 + w * 64 + mf * 16 + lg * 4 + rg;
                if (po < N) q4[po] = fast_sigmoid(rs[mf][rg] + b3v);
            }
    }
}

// ---- per level: upsample + raw + boundary + 3 conflict iters, tiled in LDS ----
// occP read via (opRow,opCol) strides; q read from q4 via (qRow,qCol) strides.
// Early-exit: tiles with no raw boundary bits are pure write-through.
#define NT 512
template<int TS>
__global__ __launch_bounds__(NT) void level_kernel(
    const float* __restrict__ occP, int opRow, int opCol,
    const u8* __restrict__ calcP, int Rp,
    const float* __restrict__ q4, int qRow, int qCol,
    float* __restrict__ occOut, u8* __restrict__ calcOut, int R)
{
    constexpr int HW = TS + 8;
    __shared__ float sOcc[HW * HW], sQ[HW * HW];
    __shared__ u8 sRaw[HW * HW], sCalc[HW * HW], sCfA[HW * HW], sCfB[HW * HW];
    const int nT = (R + TS - 1) / TS;
    const int bi = blockIdx.x / nT, bj = blockIdx.x - bi * nT;
    const int fi0 = bi * TS - 4, fj0 = bj * TS - 4;
    const int tid = threadIdx.x;
    const float BAL = 0.5f;

    // phase 1: occ-interp + raw + inherited calc + strided q
    bool anyRaw = false;
    for (int c = tid; c < HW * HW; c += NT) {
        int li = c / HW, lj = c - li * HW;
        int fi = fi0 + li, fj = fj0 + lj;
        float occi = 0.5f, qv = 0.5f; u8 rw = 0, cal = 0;
        if (fi >= 0 && fi < R && fj >= 0 && fj < R) {
            int ip = fi >> 1, jp = fj >> 1;
            float tl = occP[ip * opRow + jp * opCol];
            int oi = fi & 1, oj = fj & 1;
            bool b;
            if (!oi && !oj) { occi = tl; b = false; }
            else if (oi && !oj) {
                float bl = occP[(ip + 1) * opRow + jp * opCol];
                occi = 0.5f * (tl + bl);
                b = (tl > BAL) != (bl > BAL);
            } else if (!oi && oj) {
                float tr = occP[ip * opRow + (jp + 1) * opCol];
                occi = 0.5f * (tl + tr);
                b = (tl > BAL) != (tr > BAL);
            } else {
                float bl = occP[(ip + 1) * opRow + jp * opCol];
                float tr = occP[ip * opRow + (jp + 1) * opCol];
                float br = occP[(ip + 1) * opRow + (jp + 1) * opCol];
                occi = 0.5f * (0.5f * (tl + bl) + 0.5f * (tr + br)); // exact _up2 order
                bool m0 = tl > BAL, m1 = bl > BAL, m2 = tr > BAL, m3 = br > BAL;
                b = (m0 | m1 | m2 | m3) && !(m0 & m1 & m2 & m3);
            }
            rw = b ? 1 : 0;
            if (((fi | fj) & 1) == 0) cal = calcP ? calcP[ip * Rp + jp] : 1;
            qv = q4[fi * qRow + fj * qCol];
        }
        sOcc[c] = occi; sQ[c] = qv; sRaw[c] = rw; sCalc[c] = cal;
        sCfA[c] = 0; sCfB[c] = 0;
        anyRaw |= (rw != 0);
    }

    if (__syncthreads_or(anyRaw ? 1 : 0)) {
        // phase 2: boundary = any3x3(raw) & ~calc; seed conflicts; occ select
        bool anyCf = false;
        for (int c = tid; c < HW * HW; c += NT) {
            int li = c / HW, lj = c - li * HW;
            if (li < 1 || li >= HW - 1 || lj < 1 || lj >= HW - 1) continue;
            int fi = fi0 + li, fj = fj0 + lj;
            if (fi < 0 || fi >= R || fj < 0 || fj >= R) continue;
            bool b = false;
            #pragma unroll
            for (int di = -1; di <= 1; ++di)
                #pragma unroll
                for (int dj = -1; dj <= 1; ++dj)
                    if (sRaw[(li + di) * HW + (lj + dj)]) b = true;
            b = b && !sCalc[c];
            float oi = sOcc[c], qq = sQ[c];
            u8 cf = (b && (oi - BAL) * (qq - BAL) < 0.0f) ? 1 : 0;
            if (b) { sOcc[c] = qq; sCalc[c] = 1; }
            sCfA[c] = cf;
            anyCf |= (cf != 0);
        }
        int haveCf = __syncthreads_or(anyCf ? 1 : 0);

        // 3 conflict-propagation iterations (skip when none remain)
        for (int it = 0; it < 3 && haveCf; ++it) {
            const u8* cin = (it & 1) ? sCfB : sCfA;
            u8* cout      = (it & 1) ? sCfA : sCfB;
            int lo = 2 + it, hi = HW - 2 - it;
            bool anyNc = false;
            for (int c = tid; c < HW * HW; c += NT) {
                int li = c / HW, lj = c - li * HW;
                if (li < lo || li >= hi || lj < lo || lj >= hi) continue;
                int fi = fi0 + li, fj = fj0 + lj;
                if (fi < 0 || fi >= R || fj < 0 || fj >= R) continue;
                bool any = false;
                #pragma unroll
                for (int di = -1; di <= 1; ++di)
                    #pragma unroll
                    for (int dj = -1; dj <= 1; ++dj)
                        if (cin[(li + di) * HW + (lj + dj)]) any = true;
                bool cand = any && !sCalc[c];
                float oc = sOcc[c], qq = sQ[c];
                u8 nc = (cand && (oc - BAL) * (qq - BAL) < 0.0f) ? 1 : 0;
                if (cand) { sOcc[c] = qq; sCalc[c] = 1; }
                cout[c] = nc;
                anyNc |= (nc != 0);
            }
            haveCf = __syncthreads_or(anyNc ? 1 : 0);
        }
    }

    // write core TSxTS (synchronized by the last __syncthreads_or on all paths)
    for (int c = tid; c < HW * HW; c += NT) {
        int li = c / HW, lj = c - li * HW;
        if (li < 4 || li >= HW - 4 || lj < 4 || lj >= HW - 4) continue;
        int fi = fi0 + li, fj = fj0 + lj;
        if (fi < 0 || fi >= R || fj < 0 || fj >= R) continue;
        occOut[fi * R + fj] = sOcc[c];
        calcOut[fi * R + fj] = sCalc[c];
    }
}

extern "C" void kernel_launch(void* const* d_in, const int* in_sizes, int n_in,
                              void* d_out, int out_size, void* d_ws, size_t ws_size,
                              hipStream_t stream) {
    const float* W1   = (const float*)d_in[0];
    const float* b1   = (const float*)d_in[1];
    const float* W2   = (const float*)d_in[2];
    const float* b2   = (const float*)d_in[3];
    const float* W3   = (const float*)d_in[4];
    const float* b3   = (const float*)d_in[5];
    const float* bmin = (const float*)d_in[6];
    const float* bmax = (const float*)d_in[7];

    const int RF = 513, N513 = RF * RF;

    float* q4   = (float*)d_ws;
    float* occA = q4 + N513;
    float* occB = occA + N513;
    u8* calcA = (u8*)(occB + N513);
    u8* calcB = calcA + N513;
    float* out = (float*)d_out;

    // dense eval of the 513 grid only; 515 blocks x 512 points
    eval_q4<<<(N513 + TM - 1) / TM, 512, 0, stream>>>(
        W1, b1, W2, b2, W3, b3, bmin, bmax, q4);

    // level 1 (R=65): occP = q4 stride 16 (the 33-grid), calc all-true
    level_kernel<8><<<81, NT, 0, stream>>>(
        q4, RF * 16, 16, (const u8*)nullptr, 33,
        q4, RF * 8, 8, occA, calcB, 65);
    // level 2 (R=129): q stride 4
    level_kernel<16><<<81, NT, 0, stream>>>(
        occA, 65, 1, calcB, 65,
        q4, RF * 4, 4, occB, calcA, 129);
    // level 3 (R=257): q stride 2
    level_kernel<32><<<81, NT, 0, stream>>>(
        occB, 129, 1, calcA, 129,
        q4, RF * 2, 2, occA, calcB, 257);
    // level 4 (R=513): q stride 1
    level_kernel<32><<<289, NT, 0, stream>>>(
        occA, 257, 1, calcB, 257,
        q4, RF, 1, out, calcA, 513);
}

// Round 11
// 60.705 us; speedup vs baseline: 4.1275x; 1.1928x over previous
//
#include <hip/hip_runtime.h>

typedef unsigned char u8;
typedef float f32x4 __attribute__((ext_vector_type(4)));
typedef _Float16 f16x8 __attribute__((ext_vector_type(8)));

#define DIM 128
#define TM  128   // points per block (4 waves x 32 points)

__device__ __forceinline__ float fast_tanh(float x) {
    // tanh(x) = 1 - 2/(exp2(2x*log2e)+1); exact +-1 saturation via inf->0
    float e = __builtin_amdgcn_exp2f(x * 2.885390081777927f);
    return 1.0f - 2.0f * __builtin_amdgcn_rcpf(e + 1.0f);
}
__device__ __forceinline__ float fast_sigmoid(float x) {
    float e = __builtin_amdgcn_exp2f(x * -1.4426950408889634f);
    return __builtin_amdgcn_rcpf(1.0f + e);
}

// ---- dense MLP eval of the 513x513 grid only ----
// (coarser grids are exact subsets: u=(j*2^s)/512 == j/(R_l-1), bit-identical)
// 4 waves/block, each wave: 32 points (2 A-frags) x 128 out-dims, W2^T fp16 LDS.
// mf=2 keeps regs at 64 VGPR + 64 AGPR = 128 -> 4 waves/SIMD; 256-thr blocks
// give finer CU packing than 512 (round-10 lesson: mf=4's 224 regs -> 2 waves).
__global__ __launch_bounds__(256, 4) void eval_q4(
    const float* __restrict__ W1, const float* __restrict__ b1,
    const float* __restrict__ W2, const float* __restrict__ b2,
    const float* __restrict__ W3, const float* __restrict__ b3,
    const float* __restrict__ bmin, const float* __restrict__ bmax,
    float* __restrict__ q4)
{
    __shared__ __align__(16) _Float16 sW2T[DIM * DIM];   // 32 KB

    const int R = 513;
    const int N = R * R;                 // 263169
    const int tid = threadIdx.x;
    const int m0 = blockIdx.x * TM;

    // ---- stage W2T into LDS (fp16, XOR-swizzled 16B chunks) ----
    #pragma unroll
    for (int s = 0; s < 8; ++s) {
        int chunk = s * 256 + tid;       // 0..2047
        int n = chunk & 127, ko = chunk >> 7;
        f16x8 v;
        #pragma unroll
        for (int qq = 0; qq < 8; ++qq)
            v[qq] = (_Float16)W2[(ko * 8 + qq) * DIM + n];   // coalesced over n
        int slot = ko ^ (n & 15);
        *(f16x8*)&sW2T[n * DIM + slot * 8] = v;
    }

    const int w = tid >> 6, lane = tid & 63;
    const int l15 = lane & 15, lg = lane >> 4;

    const float inv = 1.0f / 512.0f;     // exact
    const float bx0 = bmin[0], by0 = bmin[1];
    const float sx = bmax[0] - bx0, sy = bmax[1] - by0;
    float xs[2], ys[2];
    #pragma unroll
    for (int mf = 0; mf < 2; ++mf) {
        int pi = m0 + w * 32 + mf * 16 + l15;
        int pg = (pi < N) ? pi : N - 1;
        int gi = pg / R, gj = pg - gi * R;
        xs[mf] = bx0 + (float)gj * inv * sx;
        ys[mf] = by0 + (float)gi * inv * sy;
    }

    f32x4 acc[2][8];
    #pragma unroll
    for (int mf = 0; mf < 2; ++mf)
        #pragma unroll
        for (int nf = 0; nf < 8; ++nf) acc[mf][nf] = (f32x4)(0.0f);

    __syncthreads();

    #pragma unroll
    for (int kf = 0; kf < 4; ++kf) {
        const int kbase = kf * 32 + lg * 8;
        f16x8 bh[8];
        #pragma unroll
        for (int nf = 0; nf < 8; ++nf) {
            int c = nf * 16 + l15;
            int slot = (kf * 4 + lg) ^ l15;   // matches write swizzle (c&15==l15)
            bh[nf] = *(const f16x8*)&sW2T[c * DIM + slot * 8];
        }
        f32x4 wxa = *(const f32x4*)&W1[kbase];
        f32x4 wxb = *(const f32x4*)&W1[kbase + 4];
        f32x4 wya = *(const f32x4*)&W1[DIM + kbase];
        f32x4 wyb = *(const f32x4*)&W1[DIM + kbase + 4];
        f32x4 b1a = *(const f32x4*)&b1[kbase];
        f32x4 b1b = *(const f32x4*)&b1[kbase + 4];
        f16x8 ah[2];
        #pragma unroll
        for (int mf = 0; mf < 2; ++mf) {
            float x = xs[mf], y = ys[mf];
            #pragma unroll
            for (int qq = 0; qq < 4; ++qq)
                ah[mf][qq] = (_Float16)fast_tanh(fmaf(x, wxa[qq], fmaf(y, wya[qq], b1a[qq])));
            #pragma unroll
            for (int qq = 0; qq < 4; ++qq)
                ah[mf][4 + qq] = (_Float16)fast_tanh(fmaf(x, wxb[qq], fmaf(y, wyb[qq], b1b[qq])));
        }
        #pragma unroll
        for (int nf = 0; nf < 8; ++nf)
            #pragma unroll
            for (int mf = 0; mf < 2; ++mf)
                acc[mf][nf] = __builtin_amdgcn_mfma_f32_16x16x32_f16(ah[mf], bh[nf], acc[mf][nf], 0, 0, 0);
    }

    // epilogue in registers; C/D: row = w*32+mf*16+lg*4+rg, col = nf*16+l15
    float rs[2][4] = {{0,0,0,0},{0,0,0,0}};
    #pragma unroll
    for (int nf = 0; nf < 8; ++nf) {
        int c = nf * 16 + l15;
        float w3v = W3[c], b2v = b2[c];
        #pragma unroll
        for (int mf = 0; mf < 2; ++mf)
            #pragma unroll
            for (int rg = 0; rg < 4; ++rg)
                rs[mf][rg] += fast_tanh(acc[mf][nf][rg] + b2v) * w3v;
    }
    #pragma unroll
    for (int mf = 0; mf < 2; ++mf)
        #pragma unroll
        for (int rg = 0; rg < 4; ++rg) {
            float v = rs[mf][rg];
            v += __shfl_xor(v, 1);
            v += __shfl_xor(v, 2);
            v += __shfl_xor(v, 4);
            v += __shfl_xor(v, 8);
            rs[mf][rg] = v;
        }
    if (l15 == 0) {
        float b3v = b3[0];
        #pragma unroll
        for (int mf = 0; mf < 2; ++mf)
            #pragma unroll
            for (int rg = 0; rg < 4; ++rg) {
                int po = m0 + w * 32 + mf * 16 + lg * 4 + rg;
                if (po < N) q4[po] = fast_sigmoid(rs[mf][rg] + b3v);
            }
    }
}

// ---- per level: upsample + raw + boundary + 3 conflict iters, tiled in LDS ----
// occP read via (opRow,opCol) strides; q read from q4 via (qRow,qCol) strides.
// Early-exit: tiles with no raw boundary bits are pure write-through.
#define NT 512
template<int TS>
__global__ __launch_bounds__(NT) void level_kernel(
    const float* __restrict__ occP, int opRow, int opCol,
    const u8* __restrict__ calcP, int Rp,
    const float* __restrict__ q4, int qRow, int qCol,
    float* __restrict__ occOut, u8* __restrict__ calcOut, int R)
{
    constexpr int HW = TS + 8;
    __shared__ float sOcc[HW * HW], sQ[HW * HW];
    __shared__ u8 sRaw[HW * HW], sCalc[HW * HW], sCfA[HW * HW], sCfB[HW * HW];
    const int nT = (R + TS - 1) / TS;
    const int bi = blockIdx.x / nT, bj = blockIdx.x - bi * nT;
    const int fi0 = bi * TS - 4, fj0 = bj * TS - 4;
    const int tid = threadIdx.x;
    const float BAL = 0.5f;

    // phase 1: occ-interp + raw + inherited calc + strided q
    bool anyRaw = false;
    for (int c = tid; c < HW * HW; c += NT) {
        int li = c / HW, lj = c - li * HW;
        int fi = fi0 + li, fj = fj0 + lj;
        float occi = 0.5f, qv = 0.5f; u8 rw = 0, cal = 0;
        if (fi >= 0 && fi < R && fj >= 0 && fj < R) {
            int ip = fi >> 1, jp = fj >> 1;
            float tl = occP[ip * opRow + jp * opCol];
            int oi = fi & 1, oj = fj & 1;
            bool b;
            if (!oi && !oj) { occi = tl; b = false; }
            else if (oi && !oj) {
                float bl = occP[(ip + 1) * opRow + jp * opCol];
                occi = 0.5f * (tl + bl);
                b = (tl > BAL) != (bl > BAL);
            } else if (!oi && oj) {
                float tr = occP[ip * opRow + (jp + 1) * opCol];
                occi = 0.5f * (tl + tr);
                b = (tl > BAL) != (tr > BAL);
            } else {
                float bl = occP[(ip + 1) * opRow + jp * opCol];
                float tr = occP[ip * opRow + (jp + 1) * opCol];
                float br = occP[(ip + 1) * opRow + (jp + 1) * opCol];
                occi = 0.5f * (0.5f * (tl + bl) + 0.5f * (tr + br)); // exact _up2 order
                bool m0 = tl > BAL, m1 = bl > BAL, m2 = tr > BAL, m3 = br > BAL;
                b = (m0 | m1 | m2 | m3) && !(m0 & m1 & m2 & m3);
            }
            rw = b ? 1 : 0;
            if (((fi | fj) & 1) == 0) cal = calcP ? calcP[ip * Rp + jp] : 1;
            qv = q4[fi * qRow + fj * qCol];
        }
        sOcc[c] = occi; sQ[c] = qv; sRaw[c] = rw; sCalc[c] = cal;
        sCfA[c] = 0; sCfB[c] = 0;
        anyRaw |= (rw != 0);
    }

    if (__syncthreads_or(anyRaw ? 1 : 0)) {
        // phase 2: boundary = any3x3(raw) & ~calc; seed conflicts; occ select
        bool anyCf = false;
        for (int c = tid; c < HW * HW; c += NT) {
            int li = c / HW, lj = c - li * HW;
            if (li < 1 || li >= HW - 1 || lj < 1 || lj >= HW - 1) continue;
            int fi = fi0 + li, fj = fj0 + lj;
            if (fi < 0 || fi >= R || fj < 0 || fj >= R) continue;
            bool b = false;
            #pragma unroll
            for (int di = -1; di <= 1; ++di)
                #pragma unroll
                for (int dj = -1; dj <= 1; ++dj)
                    if (sRaw[(li + di) * HW + (lj + dj)]) b = true;
            b = b && !sCalc[c];
            float oi = sOcc[c], qq = sQ[c];
            u8 cf = (b && (oi - BAL) * (qq - BAL) < 0.0f) ? 1 : 0;
            if (b) { sOcc[c] = qq; sCalc[c] = 1; }
            sCfA[c] = cf;
            anyCf |= (cf != 0);
        }
        int haveCf = __syncthreads_or(anyCf ? 1 : 0);

        // 3 conflict-propagation iterations (skip when none remain)
        for (int it = 0; it < 3 && haveCf; ++it) {
            const u8* cin = (it & 1) ? sCfB : sCfA;
            u8* cout      = (it & 1) ? sCfA : sCfB;
            int lo = 2 + it, hi = HW - 2 - it;
            bool anyNc = false;
            for (int c = tid; c < HW * HW; c += NT) {
                int li = c / HW, lj = c - li * HW;
                if (li < lo || li >= hi || lj < lo || lj >= hi) continue;
                int fi = fi0 + li, fj = fj0 + lj;
                if (fi < 0 || fi >= R || fj < 0 || fj >= R) continue;
                bool any = false;
                #pragma unroll
                for (int di = -1; di <= 1; ++di)
                    #pragma unroll
                    for (int dj = -1; dj <= 1; ++dj)
                        if (cin[(li + di) * HW + (lj + dj)]) any = true;
                bool cand = any && !sCalc[c];
                float oc = sOcc[c], qq = sQ[c];
                u8 nc = (cand && (oc - BAL) * (qq - BAL) < 0.0f) ? 1 : 0;
                if (cand) { sOcc[c] = qq; sCalc[c] = 1; }
                cout[c] = nc;
                anyNc |= (nc != 0);
            }
            haveCf = __syncthreads_or(anyNc ? 1 : 0);
        }
    }

    // write core TSxTS (synchronized by the last __syncthreads_or on all paths)
    for (int c = tid; c < HW * HW; c += NT) {
        int li = c / HW, lj = c - li * HW;
        if (li < 4 || li >= HW - 4 || lj < 4 || lj >= HW - 4) continue;
        int fi = fi0 + li, fj = fj0 + lj;
        if (fi < 0 || fi >= R || fj < 0 || fj >= R) continue;
        occOut[fi * R + fj] = sOcc[c];
        calcOut[fi * R + fj] = sCalc[c];
    }
}

extern "C" void kernel_launch(void* const* d_in, const int* in_sizes, int n_in,
                              void* d_out, int out_size, void* d_ws, size_t ws_size,
                              hipStream_t stream) {
    const float* W1   = (const float*)d_in[0];
    const float* b1   = (const float*)d_in[1];
    const float* W2   = (const float*)d_in[2];
    const float* b2   = (const float*)d_in[3];
    const float* W3   = (const float*)d_in[4];
    const float* b3   = (const float*)d_in[5];
    const float* bmin = (const float*)d_in[6];
    const float* bmax = (const float*)d_in[7];

    const int RF = 513, N513 = RF * RF;

    float* q4   = (float*)d_ws;
    float* occA = q4 + N513;
    float* occB = occA + N513;
    u8* calcA = (u8*)(occB + N513);
    u8* calcB = calcA + N513;
    float* out = (float*)d_out;

    // dense eval of the 513 grid only; 2057 blocks x 128 points
    eval_q4<<<(N513 + TM - 1) / TM, 256, 0, stream>>>(
        W1, b1, W2, b2, W3, b3, bmin, bmax, q4);

    // level 1 (R=65): occP = q4 stride 16 (the 33-grid), calc all-true
    level_kernel<8><<<81, NT, 0, stream>>>(
        q4, RF * 16, 16, (const u8*)nullptr, 33,
        q4, RF * 8, 8, occA, calcB, 65);
    // level 2 (R=129): q stride 4
    level_kernel<16><<<81, NT, 0, stream>>>(
        occA, 65, 1, calcB, 65,
        q4, RF * 4, 4, occB, calcA, 129);
    // level 3 (R=257): q stride 2
    level_kernel<32><<<81, NT, 0, stream>>>(
        occB, 129, 1, calcA, 129,
        q4, RF * 2, 2, occA, calcB, 257);
    // level 4 (R=513): q stride 1
    level_kernel<32><<<289, NT, 0, stream>>>(
        occA, 257, 1, calcB, 257,
        q4, RF, 1, out, calcA, 513);
}

// Round 12
// 54.160 us; speedup vs baseline: 4.6263x; 1.1209x over previous
//
#include <hip/hip_runtime.h>

typedef unsigned char u8;
typedef float f32x4 __attribute__((ext_vector_type(4)));
typedef _Float16 f16x8 __attribute__((ext_vector_type(8)));

#define DIM 128
#define TM  128   // eval: points per block (4 waves x 32 points)

__device__ __forceinline__ float fast_tanh(float x) {
    // tanh(x) = 1 - 2/(exp2(2x*log2e)+1); exact +-1 saturation via inf->0
    float e = __builtin_amdgcn_exp2f(x * 2.885390081777927f);
    return 1.0f - 2.0f * __builtin_amdgcn_rcpf(e + 1.0f);
}
__device__ __forceinline__ float fast_sigmoid(float x) {
    float e = __builtin_amdgcn_exp2f(x * -1.4426950408889634f);
    return __builtin_amdgcn_rcpf(1.0f + e);
}

// ---- dense MLP eval of the 513x513 grid only (round-11 best) ----
__global__ __launch_bounds__(256, 4) void eval_q4(
    const float* __restrict__ W1, const float* __restrict__ b1,
    const float* __restrict__ W2, const float* __restrict__ b2,
    const float* __restrict__ W3, const float* __restrict__ b3,
    const float* __restrict__ bmin, const float* __restrict__ bmax,
    float* __restrict__ q4)
{
    __shared__ __align__(16) _Float16 sW2T[DIM * DIM];   // 32 KB

    const int R = 513;
    const int N = R * R;                 // 263169
    const int tid = threadIdx.x;
    const int m0 = blockIdx.x * TM;

    #pragma unroll
    for (int s = 0; s < 8; ++s) {
        int chunk = s * 256 + tid;       // 0..2047
        int n = chunk & 127, ko = chunk >> 7;
        f16x8 v;
        #pragma unroll
        for (int qq = 0; qq < 8; ++qq)
            v[qq] = (_Float16)W2[(ko * 8 + qq) * DIM + n];   // coalesced over n
        int slot = ko ^ (n & 15);
        *(f16x8*)&sW2T[n * DIM + slot * 8] = v;
    }

    const int w = tid >> 6, lane = tid & 63;
    const int l15 = lane & 15, lg = lane >> 4;

    const float inv = 1.0f / 512.0f;     // exact
    const float bx0 = bmin[0], by0 = bmin[1];
    const float sx = bmax[0] - bx0, sy = bmax[1] - by0;
    float xs[2], ys[2];
    #pragma unroll
    for (int mf = 0; mf < 2; ++mf) {
        int pi = m0 + w * 32 + mf * 16 + l15;
        int pg = (pi < N) ? pi : N - 1;
        int gi = pg / R, gj = pg - gi * R;
        xs[mf] = bx0 + (float)gj * inv * sx;
        ys[mf] = by0 + (float)gi * inv * sy;
    }

    f32x4 acc[2][8];
    #pragma unroll
    for (int mf = 0; mf < 2; ++mf)
        #pragma unroll
        for (int nf = 0; nf < 8; ++nf) acc[mf][nf] = (f32x4)(0.0f);

    __syncthreads();

    #pragma unroll
    for (int kf = 0; kf < 4; ++kf) {
        const int kbase = kf * 32 + lg * 8;
        f16x8 bh[8];
        #pragma unroll
        for (int nf = 0; nf < 8; ++nf) {
            int c = nf * 16 + l15;
            int slot = (kf * 4 + lg) ^ l15;   // matches write swizzle (c&15==l15)
            bh[nf] = *(const f16x8*)&sW2T[c * DIM + slot * 8];
        }
        f32x4 wxa = *(const f32x4*)&W1[kbase];
        f32x4 wxb = *(const f32x4*)&W1[kbase + 4];
        f32x4 wya = *(const f32x4*)&W1[DIM + kbase];
        f32x4 wyb = *(const f32x4*)&W1[DIM + kbase + 4];
        f32x4 b1a = *(const f32x4*)&b1[kbase];
        f32x4 b1b = *(const f32x4*)&b1[kbase + 4];
        f16x8 ah[2];
        #pragma unroll
        for (int mf = 0; mf < 2; ++mf) {
            float x = xs[mf], y = ys[mf];
            #pragma unroll
            for (int qq = 0; qq < 4; ++qq)
                ah[mf][qq] = (_Float16)fast_tanh(fmaf(x, wxa[qq], fmaf(y, wya[qq], b1a[qq])));
            #pragma unroll
            for (int qq = 0; qq < 4; ++qq)
                ah[mf][4 + qq] = (_Float16)fast_tanh(fmaf(x, wxb[qq], fmaf(y, wyb[qq], b1b[qq])));
        }
        #pragma unroll
        for (int nf = 0; nf < 8; ++nf)
            #pragma unroll
            for (int mf = 0; mf < 2; ++mf)
                acc[mf][nf] = __builtin_amdgcn_mfma_f32_16x16x32_f16(ah[mf], bh[nf], acc[mf][nf], 0, 0, 0);
    }

    float rs[2][4] = {{0,0,0,0},{0,0,0,0}};
    #pragma unroll
    for (int nf = 0; nf < 8; ++nf) {
        int c = nf * 16 + l15;
        float w3v = W3[c], b2v = b2[c];
        #pragma unroll
        for (int mf = 0; mf < 2; ++mf)
            #pragma unroll
            for (int rg = 0; rg < 4; ++rg)
                rs[mf][rg] += fast_tanh(acc[mf][nf][rg] + b2v) * w3v;
    }
    #pragma unroll
    for (int mf = 0; mf < 2; ++mf)
        #pragma unroll
        for (int rg = 0; rg < 4; ++rg) {
            float v = rs[mf][rg];
            v += __shfl_xor(v, 1);
            v += __shfl_xor(v, 2);
            v += __shfl_xor(v, 4);
            v += __shfl_xor(v, 8);
            rs[mf][rg] = v;
        }
    if (l15 == 0) {
        float b3v = b3[0];
        #pragma unroll
        for (int mf = 0; mf < 2; ++mf)
            #pragma unroll
            for (int rg = 0; rg < 4; ++rg) {
                int po = m0 + w * 32 + mf * 16 + lg * 4 + rg;
                if (po < N) q4[po] = fast_sigmoid(rs[mf][rg] + b3v);
            }
    }
}

// ---- per level: upsample + raw + boundary + 3 conflict iters, tiled in LDS ----
// NT == HW*HW: every barrier-separated phase is EXACTLY ONE grid-stride
// iteration -> minimal critical path for this latency-bound stencil chain.
template<int TS, int NT>
__global__ __launch_bounds__(NT) void level_kernel(
    const float* __restrict__ occP, int opRow, int opCol,
    const u8* __restrict__ calcP, int Rp,
    const float* __restrict__ q4, int qRow, int qCol,
    float* __restrict__ occOut, u8* __restrict__ calcOut, int R)
{
    constexpr int HW = TS + 8;
    __shared__ float sOcc[HW * HW], sQ[HW * HW];
    __shared__ u8 sRaw[HW * HW], sCalc[HW * HW], sCfA[HW * HW], sCfB[HW * HW];
    const int nT = (R + TS - 1) / TS;
    const int bi = blockIdx.x / nT, bj = blockIdx.x - bi * nT;
    const int fi0 = bi * TS - 4, fj0 = bj * TS - 4;
    const int tid = threadIdx.x;
    const float BAL = 0.5f;

    // phase 1: occ-interp + raw + inherited calc + strided q
    bool anyRaw = false;
    for (int c = tid; c < HW * HW; c += NT) {
        int li = c / HW, lj = c - li * HW;
        int fi = fi0 + li, fj = fj0 + lj;
        float occi = 0.5f, qv = 0.5f; u8 rw = 0, cal = 0;
        if (fi >= 0 && fi < R && fj >= 0 && fj < R) {
            int ip = fi >> 1, jp = fj >> 1;
            float tl = occP[ip * opRow + jp * opCol];
            int oi = fi & 1, oj = fj & 1;
            bool b;
            if (!oi && !oj) { occi = tl; b = false; }
            else if (oi && !oj) {
                float bl = occP[(ip + 1) * opRow + jp * opCol];
                occi = 0.5f * (tl + bl);
                b = (tl > BAL) != (bl > BAL);
            } else if (!oi && oj) {
                float tr = occP[ip * opRow + (jp + 1) * opCol];
                occi = 0.5f * (tl + tr);
                b = (tl > BAL) != (tr > BAL);
            } else {
                float bl = occP[(ip + 1) * opRow + jp * opCol];
                float tr = occP[ip * opRow + (jp + 1) * opCol];
                float br = occP[(ip + 1) * opRow + (jp + 1) * opCol];
                occi = 0.5f * (0.5f * (tl + bl) + 0.5f * (tr + br)); // exact _up2 order
                bool m0 = tl > BAL, m1 = bl > BAL, m2 = tr > BAL, m3 = br > BAL;
                b = (m0 | m1 | m2 | m3) && !(m0 & m1 & m2 & m3);
            }
            rw = b ? 1 : 0;
            if (((fi | fj) & 1) == 0) cal = calcP ? calcP[ip * Rp + jp] : 1;
            qv = q4[fi * qRow + fj * qCol];
        }
        sOcc[c] = occi; sQ[c] = qv; sRaw[c] = rw; sCalc[c] = cal;
        sCfA[c] = 0; sCfB[c] = 0;
        anyRaw |= (rw != 0);
    }

    if (__syncthreads_or(anyRaw ? 1 : 0)) {
        // phase 2: boundary = any3x3(raw) & ~calc; seed conflicts; occ select
        bool anyCf = false;
        for (int c = tid; c < HW * HW; c += NT) {
            int li = c / HW, lj = c - li * HW;
            int fi = fi0 + li, fj = fj0 + lj;
            if (li >= 1 && li < HW - 1 && lj >= 1 && lj < HW - 1 &&
                fi >= 0 && fi < R && fj >= 0 && fj < R) {
                bool b = false;
                #pragma unroll
                for (int di = -1; di <= 1; ++di)
                    #pragma unroll
                    for (int dj = -1; dj <= 1; ++dj)
                        if (sRaw[(li + di) * HW + (lj + dj)]) b = true;
                b = b && !sCalc[c];
                float oi = sOcc[c], qq = sQ[c];
                u8 cf = (b && (oi - BAL) * (qq - BAL) < 0.0f) ? 1 : 0;
                if (b) { sOcc[c] = qq; sCalc[c] = 1; }
                sCfA[c] = cf;
                anyCf |= (cf != 0);
            }
        }
        int haveCf = __syncthreads_or(anyCf ? 1 : 0);

        // 3 conflict-propagation iterations (skip when none remain)
        for (int it = 0; it < 3 && haveCf; ++it) {
            const u8* cin = (it & 1) ? sCfB : sCfA;
            u8* cout      = (it & 1) ? sCfA : sCfB;
            int lo = 2 + it, hi = HW - 2 - it;
            bool anyNc = false;
            for (int c = tid; c < HW * HW; c += NT) {
                int li = c / HW, lj = c - li * HW;
                int fi = fi0 + li, fj = fj0 + lj;
                if (li >= lo && li < hi && lj >= lo && lj < hi &&
                    fi >= 0 && fi < R && fj >= 0 && fj < R) {
                    bool any = false;
                    #pragma unroll
                    for (int di = -1; di <= 1; ++di)
                        #pragma unroll
                        for (int dj = -1; dj <= 1; ++dj)
                            if (cin[(li + di) * HW + (lj + dj)]) any = true;
                    bool cand = any && !sCalc[c];
                    float oc = sOcc[c], qq = sQ[c];
                    u8 nc = (cand && (oc - BAL) * (qq - BAL) < 0.0f) ? 1 : 0;
                    if (cand) { sOcc[c] = qq; sCalc[c] = 1; }
                    cout[c] = nc;
                    anyNc |= (nc != 0);
                }
            }
            haveCf = __syncthreads_or(anyNc ? 1 : 0);
        }
    }

    // write core TSxTS (synchronized by the last __syncthreads_or on all paths)
    for (int c = tid; c < HW * HW; c += NT) {
        int li = c / HW, lj = c - li * HW;
        if (li < 4 || li >= HW - 4 || lj < 4 || lj >= HW - 4) continue;
        int fi = fi0 + li, fj = fj0 + lj;
        if (fi < 0 || fi >= R || fj < 0 || fj >= R) continue;
        occOut[fi * R + fj] = sOcc[c];
        calcOut[fi * R + fj] = sCalc[c];
    }
}

extern "C" void kernel_launch(void* const* d_in, const int* in_sizes, int n_in,
                              void* d_out, int out_size, void* d_ws, size_t ws_size,
                              hipStream_t stream) {
    const float* W1   = (const float*)d_in[0];
    const float* b1   = (const float*)d_in[1];
    const float* W2   = (const float*)d_in[2];
    const float* b2   = (const float*)d_in[3];
    const float* W3   = (const float*)d_in[4];
    const float* b3   = (const float*)d_in[5];
    const float* bmin = (const float*)d_in[6];
    const float* bmax = (const float*)d_in[7];

    const int RF = 513, N513 = RF * RF;

    float* q4   = (float*)d_ws;
    float* occA = q4 + N513;
    float* occB = occA + N513;
    u8* calcA = (u8*)(occB + N513);
    u8* calcB = calcA + N513;
    float* out = (float*)d_out;

    // dense eval of the 513 grid only; 2057 blocks x 128 points
    eval_q4<<<(N513 + TM - 1) / TM, 256, 0, stream>>>(
        W1, b1, W2, b2, W3, b3, bmin, bmax, q4);

    // level 1 (R=65): occP = q4 stride 16 (33-grid); TS=8 -> 81 blocks, 1-iter phases
    level_kernel<8, 256><<<81, 256, 0, stream>>>(
        q4, RF * 16, 16, (const u8*)nullptr, 33,
        q4, RF * 8, 8, occA, calcB, 65);
    // level 2 (R=129): TS=16 -> 81 blocks
    level_kernel<16, 576><<<81, 576, 0, stream>>>(
        occA, 65, 1, calcB, 65,
        q4, RF * 4, 4, occB, calcA, 129);
    // level 3 (R=257): TS=16 -> 289 blocks
    level_kernel<16, 576><<<289, 576, 0, stream>>>(
        occB, 129, 1, calcA, 129,
        q4, RF * 2, 2, occA, calcB, 257);
    // level 4 (R=513): TS=16 -> 1089 blocks
    level_kernel<16, 576><<<1089, 576, 0, stream>>>(
        occA, 257, 1, calcB, 257,
        q4, RF, 1, out, calcA, 513);
}

// Round 13
// 50.265 us; speedup vs baseline: 4.9847x; 1.0775x over previous
//
#include <hip/hip_runtime.h>

typedef unsigned char u8;
typedef float f32x4 __attribute__((ext_vector_type(4)));
typedef _Float16 f16x8 __attribute__((ext_vector_type(8)));

#define DIM 128
#define TM  128   // eval: points per block (4 waves x 32 points)

__device__ __forceinline__ float fast_tanh(float x) {
    // tanh(x) = 1 - 2/(exp2(2x*log2e)+1); exact +-1 saturation via inf->0
    float e = __builtin_amdgcn_exp2f(x * 2.885390081777927f);
    return 1.0f - 2.0f * __builtin_amdgcn_rcpf(e + 1.0f);
}
__device__ __forceinline__ float fast_sigmoid(float x) {
    float e = __builtin_amdgcn_exp2f(x * -1.4426950408889634f);
    return __builtin_amdgcn_rcpf(1.0f + e);
}

// ---- dense MLP eval of the 513x513 grid only ----
// (coarser grids are exact subsets: u=(j*2^s)/512 == j/(R_l-1), bit-identical)
// 4 waves/block, 32 points/wave (mf=2), W2^T fp16 in LDS, b2 folded into acc.
__global__ __launch_bounds__(256, 4) void eval_q4(
    const float* __restrict__ W1, const float* __restrict__ b1,
    const float* __restrict__ W2, const float* __restrict__ b2,
    const float* __restrict__ W3, const float* __restrict__ b3,
    const float* __restrict__ bmin, const float* __restrict__ bmax,
    float* __restrict__ q4)
{
    __shared__ __align__(16) _Float16 sW2T[DIM * DIM];   // 32 KB

    const int R = 513;
    const int N = R * R;                 // 263169
    const int tid = threadIdx.x;
    const int m0 = blockIdx.x * TM;

    #pragma unroll
    for (int s = 0; s < 8; ++s) {
        int chunk = s * 256 + tid;       // 0..2047
        int n = chunk & 127, ko = chunk >> 7;
        f16x8 v;
        #pragma unroll
        for (int qq = 0; qq < 8; ++qq)
            v[qq] = (_Float16)W2[(ko * 8 + qq) * DIM + n];   // coalesced over n
        int slot = ko ^ (n & 15);
        *(f16x8*)&sW2T[n * DIM + slot * 8] = v;
    }

    const int w = tid >> 6, lane = tid & 63;
    const int l15 = lane & 15, lg = lane >> 4;

    const float inv = 1.0f / 512.0f;     // exact
    const float bx0 = bmin[0], by0 = bmin[1];
    const float sx = bmax[0] - bx0, sy = bmax[1] - by0;
    float xs[2], ys[2];
    #pragma unroll
    for (int mf = 0; mf < 2; ++mf) {
        int pi = m0 + w * 32 + mf * 16 + l15;
        int pg = (pi < N) ? pi : N - 1;
        int gi = pg / R, gj = pg - gi * R;
        xs[mf] = bx0 + (float)gj * inv * sx;
        ys[mf] = by0 + (float)gi * inv * sy;
    }

    // acc init = b2[col] (folds the bias add out of the epilogue)
    f32x4 acc[2][8];
    #pragma unroll
    for (int nf = 0; nf < 8; ++nf) {
        float b2v = b2[nf * 16 + l15];
        acc[0][nf] = (f32x4)(b2v);
        acc[1][nf] = (f32x4)(b2v);
    }

    __syncthreads();

    #pragma unroll
    for (int kf = 0; kf < 4; ++kf) {
        const int kbase = kf * 32 + lg * 8;
        f16x8 bh[8];
        #pragma unroll
        for (int nf = 0; nf < 8; ++nf) {
            int c = nf * 16 + l15;
            int slot = (kf * 4 + lg) ^ l15;   // matches write swizzle (c&15==l15)
            bh[nf] = *(const f16x8*)&sW2T[c * DIM + slot * 8];
        }
        f32x4 wxa = *(const f32x4*)&W1[kbase];
        f32x4 wxb = *(const f32x4*)&W1[kbase + 4];
        f32x4 wya = *(const f32x4*)&W1[DIM + kbase];
        f32x4 wyb = *(const f32x4*)&W1[DIM + kbase + 4];
        f32x4 b1a = *(const f32x4*)&b1[kbase];
        f32x4 b1b = *(const f32x4*)&b1[kbase + 4];
        f16x8 ah[2];
        #pragma unroll
        for (int mf = 0; mf < 2; ++mf) {
            float x = xs[mf], y = ys[mf];
            #pragma unroll
            for (int qq = 0; qq < 4; ++qq)
                ah[mf][qq] = (_Float16)fast_tanh(fmaf(x, wxa[qq], fmaf(y, wya[qq], b1a[qq])));
            #pragma unroll
            for (int qq = 0; qq < 4; ++qq)
                ah[mf][4 + qq] = (_Float16)fast_tanh(fmaf(x, wxb[qq], fmaf(y, wyb[qq], b1b[qq])));
        }
        #pragma unroll
        for (int nf = 0; nf < 8; ++nf)
            #pragma unroll
            for (int mf = 0; mf < 2; ++mf)
                acc[mf][nf] = __builtin_amdgcn_mfma_f32_16x16x32_f16(ah[mf], bh[nf], acc[mf][nf], 0, 0, 0);
    }

    // epilogue; C/D: row = w*32+mf*16+lg*4+rg, col = nf*16+l15
    float rs[2][4] = {{0,0,0,0},{0,0,0,0}};
    #pragma unroll
    for (int nf = 0; nf < 8; ++nf) {
        float w3v = W3[nf * 16 + l15];
        #pragma unroll
        for (int mf = 0; mf < 2; ++mf)
            #pragma unroll
            for (int rg = 0; rg < 4; ++rg)
                rs[mf][rg] += fast_tanh(acc[mf][nf][rg]) * w3v;
    }
    #pragma unroll
    for (int mf = 0; mf < 2; ++mf)
        #pragma unroll
        for (int rg = 0; rg < 4; ++rg) {
            float v = rs[mf][rg];
            v += __shfl_xor(v, 1);
            v += __shfl_xor(v, 2);
            v += __shfl_xor(v, 4);
            v += __shfl_xor(v, 8);
            rs[mf][rg] = v;
        }
    if (l15 == 0) {
        float b3v = b3[0];
        #pragma unroll
        for (int mf = 0; mf < 2; ++mf)
            #pragma unroll
            for (int rg = 0; rg < 4; ++rg) {
                int po = m0 + w * 32 + mf * 16 + lg * 4 + rg;
                if (po < N) q4[po] = fast_sigmoid(rs[mf][rg] + b3v);
            }
    }
}

// ---- per level: upsample + raw + boundary + 3 conflict iters ----
// NT == HW*HW: one thread per cell. occ/q/calc live in REGISTERS (only raw
// and the conflict flags are read cross-thread -> 3 u8 LDS arrays, ~1.7KB).
// q4 load issued before the first barrier: latency hides under phase 1;
// write-through tiles never wait on it.
template<int TS, int NT>
__global__ __launch_bounds__(NT) void level_kernel(
    const float* __restrict__ occP, int opRow, int opCol,
    const u8* __restrict__ calcP, int Rp,
    const float* __restrict__ q4, int qRow, int qCol,
    float* __restrict__ occOut, u8* __restrict__ calcOut, int R)
{
    constexpr int HW = TS + 8;
    __shared__ u8 sRaw[HW * HW], sCfA[HW * HW], sCfB[HW * HW];
    const int nT = (R + TS - 1) / TS;
    const int bi = blockIdx.x / nT, bj = blockIdx.x - bi * nT;
    const int fi0 = bi * TS - 4, fj0 = bj * TS - 4;
    const int c = threadIdx.x;           // this thread's cell
    const int li = c / HW, lj = c - li * HW;
    const int fi = fi0 + li, fj = fj0 + lj;
    const bool inG = (fi >= 0 && fi < R && fj >= 0 && fj < R);
    const float BAL = 0.5f;

    // phase 1: upsample + raw + inherited calc (regs); issue q load early
    float occ = 0.5f, qv = 0.5f;
    u8 rw = 0; bool cal = false;
    if (inG) qv = q4[fi * qRow + fj * qCol];      // in flight; waited on at use
    if (inG) {
        int ip = fi >> 1, jp = fj >> 1;
        float tl = occP[ip * opRow + jp * opCol];
        int oi = fi & 1, oj = fj & 1;
        bool b;
        if (!oi && !oj) { occ = tl; b = false; }
        else if (oi && !oj) {
            float bl = occP[(ip + 1) * opRow + jp * opCol];
            occ = 0.5f * (tl + bl);
            b = (tl > BAL) != (bl > BAL);
        } else if (!oi && oj) {
            float tr = occP[ip * opRow + (jp + 1) * opCol];
            occ = 0.5f * (tl + tr);
            b = (tl > BAL) != (tr > BAL);
        } else {
            float bl = occP[(ip + 1) * opRow + jp * opCol];
            float tr = occP[ip * opRow + (jp + 1) * opCol];
            float br = occP[(ip + 1) * opRow + (jp + 1) * opCol];
            occ = 0.5f * (0.5f * (tl + bl) + 0.5f * (tr + br));  // exact _up2 order
            bool m0 = tl > BAL, m1 = bl > BAL, m2 = tr > BAL, m3 = br > BAL;
            b = (m0 | m1 | m2 | m3) && !(m0 & m1 & m2 & m3);
        }
        rw = b ? 1 : 0;
        if (((fi | fj) & 1) == 0) cal = calcP ? (calcP[ip * Rp + jp] != 0) : true;
    }
    sRaw[c] = rw; sCfA[c] = 0; sCfB[c] = 0;

    if (__syncthreads_or(rw)) {
        // phase 2: boundary = any3x3(raw) & ~calc; seed conflicts; occ select
        u8 cf = 0;
        if (li >= 1 && li < HW - 1 && lj >= 1 && lj < HW - 1 && inG) {
            bool b = false;
            #pragma unroll
            for (int di = -1; di <= 1; ++di)
                #pragma unroll
                for (int dj = -1; dj <= 1; ++dj)
                    if (sRaw[(li + di) * HW + (lj + dj)]) b = true;
            b = b && !cal;
            cf = (b && (occ - BAL) * (qv - BAL) < 0.0f) ? 1 : 0;
            if (b) { occ = qv; cal = true; }
            sCfA[c] = cf;
        }
        int haveCf = __syncthreads_or((int)cf);

        // 3 conflict-propagation iterations (skip when none remain)
        #pragma unroll
        for (int it = 0; it < 3; ++it) {
            if (!haveCf) break;
            const u8* cin = (it & 1) ? sCfB : sCfA;
            u8* cout      = (it & 1) ? sCfA : sCfB;
            int lo = 2 + it, hi = HW - 2 - it;
            u8 nc = 0;
            if (li >= lo && li < hi && lj >= lo && lj < hi && inG) {
                bool any = false;
                #pragma unroll
                for (int di = -1; di <= 1; ++di)
                    #pragma unroll
                    for (int dj = -1; dj <= 1; ++dj)
                        if (cin[(li + di) * HW + (lj + dj)]) any = true;
                bool cand = any && !cal;
                nc = (cand && (occ - BAL) * (qv - BAL) < 0.0f) ? 1 : 0;
                if (cand) { occ = qv; cal = true; }
                cout[c] = nc;
            }
            haveCf = __syncthreads_or((int)nc);
        }
    }

    // write core TSxTS
    if (li >= 4 && li < HW - 4 && lj >= 4 && lj < HW - 4 && inG) {
        occOut[fi * R + fj] = occ;
        calcOut[fi * R + fj] = cal ? 1 : 0;
    }
}

extern "C" void kernel_launch(void* const* d_in, const int* in_sizes, int n_in,
                              void* d_out, int out_size, void* d_ws, size_t ws_size,
                              hipStream_t stream) {
    const float* W1   = (const float*)d_in[0];
    const float* b1   = (const float*)d_in[1];
    const float* W2   = (const float*)d_in[2];
    const float* b2   = (const float*)d_in[3];
    const float* W3   = (const float*)d_in[4];
    const float* b3   = (const float*)d_in[5];
    const float* bmin = (const float*)d_in[6];
    const float* bmax = (const float*)d_in[7];

    const int RF = 513, N513 = RF * RF;

    float* q4   = (float*)d_ws;
    float* occA = q4 + N513;
    float* occB = occA + N513;
    u8* calcA = (u8*)(occB + N513);
    u8* calcB = calcA + N513;
    float* out = (float*)d_out;

    // dense eval of the 513 grid only; 2057 blocks x 128 points
    eval_q4<<<(N513 + TM - 1) / TM, 256, 0, stream>>>(
        W1, b1, W2, b2, W3, b3, bmin, bmax, q4);

    // level 1 (R=65): occP = q4 stride 16 (33-grid); TS=8 -> 81 blocks
    level_kernel<8, 256><<<81, 256, 0, stream>>>(
        q4, RF * 16, 16, (const u8*)nullptr, 33,
        q4, RF * 8, 8, occA, calcB, 65);
    // level 2 (R=129): TS=16 -> 81 blocks
    level_kernel<16, 576><<<81, 576, 0, stream>>>(
        occA, 65, 1, calcB, 65,
        q4, RF * 4, 4, occB, calcA, 129);
    // level 3 (R=257): TS=16 -> 289 blocks
    level_kernel<16, 576><<<289, 576, 0, stream>>>(
        occB, 129, 1, calcA, 129,
        q4, RF * 2, 2, occA, calcB, 257);
    // level 4 (R=513): TS=16 -> 1089 blocks
    level_kernel<16, 576><<<1089, 576, 0, stream>>>(
        occA, 257, 1, calcB, 257,
        q4, RF, 1, out, calcA, 513);
}